// Round 5
// baseline (357.469 us; speedup 1.0000x reference)
//
#include <hip/hip_runtime.h>
#include <hip/hip_bf16.h>
#include <math.h>

// MultiHeadDiffAttention, MI355X. Round 5: VALU-trimmed attention.
//  - Q pre-scaled by 0.125*log2(e) in projection epilogue (exp2 direct)
//  - P fp32->bf16 via v_perm truncation (1 inst / 2 elems)
//  - l computed by ones-vector MFMA (C-layout matches epilogue rows; no shuffles)
//  - kv-split x4, launch_bounds(256,4) for occupancy
// B=2 S=2048 E=1024 H=8 DH=128 F=64.
// ws layout (64 MB):
//   [Oacc 32MB f32 (xb bf16 overlays head, dead before zero_ws)]
//   [wob 2MB][wqb 2MB <- Lacc overlays after gemm_qkv][wkb 2][wvb 2]
//   [Qb 8MB <- Nb overlays after attn][Kb 8MB][Vtb 8MB]

#define SDIM 2048
#define EDIM 1024
#define HDIM 8
#define DHDIM 128

typedef unsigned short u16;
typedef __attribute__((ext_vector_type(8))) short bf16x8;
typedef __attribute__((ext_vector_type(4))) u16 u16x4;
typedef __attribute__((ext_vector_type(8))) u16 u16x8;
typedef __attribute__((ext_vector_type(4))) float f32x4;

__device__ __forceinline__ u16 bf16rne(float f) {
    unsigned int u = __float_as_uint(f);
    u += 0x7fff + ((u >> 16) & 1);
    return (u16)(u >> 16);
}

__device__ __forceinline__ void gload16(void* lds, const void* g) {
    __builtin_amdgcn_global_load_lds(
        (const __attribute__((address_space(1))) unsigned int*)g,
        (__attribute__((address_space(3))) unsigned int*)lds, 16, 0, 0);
}

constexpr int GM = 4096, GN = 1024, GK = 1024;

// ------------------------------------------------------------------
// cast fp32 -> bf16: x (4M) + Wq/Wk/Wv/Wo (1M each).
// ------------------------------------------------------------------
__global__ __launch_bounds__(256) void cast_bf16(
    const float* __restrict__ x,  const float* __restrict__ wq,
    const float* __restrict__ wk, const float* __restrict__ wv,
    const float* __restrict__ wo,
    u16* __restrict__ xb,  u16* __restrict__ wqb, u16* __restrict__ wkb,
    u16* __restrict__ wvb, u16* __restrict__ wob)
{
    int bid = blockIdx.x;
    const float* src; u16* dst; int lb;
    if (bid < 2048)      { src = x;  dst = xb;  lb = bid; }
    else if (bid < 2560) { src = wq; dst = wqb; lb = bid - 2048; }
    else if (bid < 3072) { src = wk; dst = wkb; lb = bid - 2560; }
    else if (bid < 3584) { src = wv; dst = wvb; lb = bid - 3072; }
    else                 { src = wo; dst = wob; lb = bid - 3584; }
    size_t i = ((size_t)lb * 256 + threadIdx.x) * 8;
    float4 a = *(const float4*)&src[i];
    float4 b = *(const float4*)&src[i + 4];
    u16x8 o;
    o[0] = bf16rne(a.x); o[1] = bf16rne(a.y); o[2] = bf16rne(a.z); o[3] = bf16rne(a.w);
    o[4] = bf16rne(b.x); o[5] = bf16rne(b.y); o[6] = bf16rne(b.z); o[7] = bf16rne(b.w);
    *(u16x8*)&dst[i] = o;
}

// ------------------------------------------------------------------
// zero Oacc (8.39M f32) + Lacc (64K f32)
// ------------------------------------------------------------------
__global__ __launch_bounds__(256) void zero_ws(
    float* __restrict__ Oacc, float* __restrict__ Lacc)
{
    int bid = blockIdx.x;
    const f32x4 z = (f32x4){0.f, 0.f, 0.f, 0.f};
    if (bid < 8192) {
        *(f32x4*)&Oacc[((size_t)bid * 256 + threadIdx.x) * 4] = z;
    } else {
        *(f32x4*)&Lacc[((size_t)(bid - 8192) * 256 + threadIdx.x) * 4] = z;
    }
}

// ------------------------------------------------------------------
// bf16 MFMA GEMM core: C = A @ W^T, 128x128, BK=32. (unchanged)
// ------------------------------------------------------------------
struct GemmCore {
    f32x4 acc[4][4];
    int m0, n0, wm, wn, ln, quad;
};

__device__ __forceinline__ void gemm_core(
    GemmCore& g, const u16* __restrict__ A, const u16* __restrict__ W,
    u16* AsBase, u16* BsBase)
{
    const int tid = threadIdx.x;
    const int lane = tid & 63;
    const int wv = tid >> 6;
    g.ln = lane & 15; g.quad = lane >> 4;
    g.wm = (wv >> 1) * 64; g.wn = (wv & 1) * 64;
    g.m0 = blockIdx.y * 128; g.n0 = blockIdx.x * 128;

#pragma unroll
    for (int i = 0; i < 4; ++i)
#pragma unroll
        for (int j = 0; j < 4; ++j)
            g.acc[i][j] = (f32x4){0.f, 0.f, 0.f, 0.f};

    const int s0 = tid, s1 = tid + 256;
    const int ar0 = s0 >> 2, ac0 = (((s0 & 3) ^ ((ar0 >> 1) & 3)) * 8);
    const int ar1 = s1 >> 2, ac1 = (((s1 & 3) ^ ((ar1 >> 1) & 3)) * 8);
    const u16* pa0 = A + (size_t)(g.m0 + ar0) * GK + ac0;
    const u16* pa1 = A + (size_t)(g.m0 + ar1) * GK + ac1;
    const u16* pb0 = W + (size_t)(g.n0 + ar0) * GK + ac0;
    const u16* pb1 = W + (size_t)(g.n0 + ar1) * GK + ac1;
    u16* la0 = AsBase + s0 * 8; u16* la1 = AsBase + s1 * 8;
    u16* lb0 = BsBase + s0 * 8; u16* lb1 = BsBase + s1 * 8;

    const int roff = ((g.quad ^ ((g.ln >> 1) & 3)) * 8);

    for (int k0 = 0; k0 < GK; k0 += 32) {
        gload16(la0, pa0 + k0);
        gload16(la1, pa1 + k0);
        gload16(lb0, pb0 + k0);
        gload16(lb1, pb1 + k0);
        __syncthreads();

        bf16x8 af[4], bfr[4];
#pragma unroll
        for (int t = 0; t < 4; ++t) {
            af[t]  = *(const bf16x8*)&AsBase[(g.wm + t * 16 + g.ln) * 32 + roff];
            bfr[t] = *(const bf16x8*)&BsBase[(g.wn + t * 16 + g.ln) * 32 + roff];
        }
#pragma unroll
        for (int i = 0; i < 4; ++i)
#pragma unroll
            for (int j = 0; j < 4; ++j)
                g.acc[i][j] = __builtin_amdgcn_mfma_f32_16x16x32_bf16(
                    af[i], bfr[j], g.acc[i][j], 0, 0, 0);
        __syncthreads();
    }
}

// z=0 -> Qb (bf16, PRE-SCALED by 0.125*log2e), z=1 -> Kb, z=2 -> Vt
__global__ __launch_bounds__(256) void gemm_qkv(
    const u16* __restrict__ A,
    const u16* __restrict__ W0, const u16* __restrict__ W1, const u16* __restrict__ W2,
    u16* __restrict__ Qb, u16* __restrict__ Kb, u16* __restrict__ Vtb)
{
    __shared__ u16 As[128 * 32];
    __shared__ u16 Bs[128 * 32];
    const int z = blockIdx.z;
    const u16* W = (z == 0) ? W0 : ((z == 1) ? W1 : W2);
    GemmCore g;
    gemm_core(g, A, W, As, Bs);

    if (z < 2) {
        const float scl = (z == 0) ? 0.125f * 1.44269504f : 1.0f;
        u16* C = (z == 0) ? Qb : Kb;
#pragma unroll
        for (int i = 0; i < 4; ++i) {
            int rb = g.m0 + g.wm + i * 16 + g.quad * 4;
#pragma unroll
            for (int r = 0; r < 4; ++r) {
                u16* crow = C + (size_t)(rb + r) * GN + g.n0 + g.wn + g.ln;
#pragma unroll
                for (int j = 0; j < 4; ++j)
                    crow[j * 16] = bf16rne(g.acc[i][j][r] * scl);
            }
        }
    } else {
        const int bb = g.m0 >> 11;
        const int sb = (g.m0 & 2047) + g.wm + g.quad * 4;
#pragma unroll
        for (int j = 0; j < 4; ++j) {
            int dhg = g.n0 + g.wn + j * 16 + g.ln;
            int hh = dhg >> 7, dh = dhg & 127;
            u16* vrow = Vtb + ((size_t)(bb * 8 + hh) * DHDIM + dh) * SDIM + sb;
#pragma unroll
            for (int i = 0; i < 4; ++i) {
                u16x4 pk;
#pragma unroll
                for (int r = 0; r < 4; ++r) pk[r] = bf16rne(g.acc[i][j][r]);
                *(u16x4*)&vrow[i * 16] = pk;
            }
        }
    }
}

// out = (A @ W.T + bias) * (1-dw), fp32 output
__global__ __launch_bounds__(256) void gemm_out(
    const u16* __restrict__ A, const u16* __restrict__ W,
    float* __restrict__ C, const float* __restrict__ bias,
    const float* __restrict__ dwp)
{
    __shared__ u16 As[128 * 32];
    __shared__ u16 Bs[128 * 32];
    GemmCore g;
    gemm_core(g, A, W, As, Bs);

    const float scale = 1.0f - dwp[0];
    float bv[4];
#pragma unroll
    for (int j = 0; j < 4; ++j) bv[j] = bias[g.n0 + g.wn + j * 16 + g.ln];
#pragma unroll
    for (int i = 0; i < 4; ++i) {
        int rb = g.m0 + g.wm + i * 16 + g.quad * 4;
#pragma unroll
        for (int r = 0; r < 4; ++r) {
            float* crow = C + (size_t)(rb + r) * GN + g.n0 + g.wn + g.ln;
#pragma unroll
            for (int j = 0; j < 4; ++j)
                crow[j * 16] = (g.acc[i][j][r] + bv[j]) * scale;
        }
    }
}

// ------------------------------------------------------------------
// MFMA diff attention v3. Block = 4 waves, 64 q rows.
// Grid (32 qtiles, 16 bh, 4 kv-parts); each block 512 kv = 16 iters.
// Q pre-scaled -> p = exp2f(s). P pack via v_perm truncation.
// l via ones-MFMA (D[q][*] = sum_k P[q][k], rows match epilogue).
// Partials additive -> fp32 atomicAdd into Oacc/Lacc.
// ------------------------------------------------------------------
__global__ __launch_bounds__(256, 4) void attn_mfma(
    const u16* __restrict__ Qb, const u16* __restrict__ Kb,
    const u16* __restrict__ Vtb,
    float* __restrict__ Oacc, float* __restrict__ Lacc)
{
    __shared__ u16 Ks[512 * 8];
    __shared__ u16 Vs[512 * 8];
    __shared__ float Ps[4][2][16][36];

    const int tid = threadIdx.x;
    const int wv   = tid >> 6;
    const int lane = tid & 63;
    const int ln = lane & 15, quad = lane >> 4;
    const int bh = blockIdx.y, b = bh >> 3, h = bh & 7;
    const int q0 = blockIdx.x * 64 + wv * 16;
    const int kvbase = blockIdx.z * 512;

    const size_t qoff = (size_t)b * SDIM * EDIM + h * DHDIM;
    const u16* qp = Qb + qoff + (size_t)(q0 + ln) * EDIM + quad * 8;
    bf16x8 aq[2][2];
    aq[0][0] = *(const bf16x8*)(qp);
    aq[0][1] = *(const bf16x8*)(qp + 32);
    aq[1][0] = *(const bf16x8*)(qp + 64);
    aq[1][1] = *(const bf16x8*)(qp + 96);

    const int sA = tid, sB = tid + 256;
    const int krA = sA >> 4, kcA = ((sA & 15) ^ (krA & 7)) * 8;
    const int krB = sB >> 4, kcB = ((sB & 15) ^ (krB & 7)) * 8;
    const u16* kgA = Kb + ((size_t)(b * SDIM + kvbase + krA)) * EDIM + h * DHDIM + kcA;
    const u16* kgB = Kb + ((size_t)(b * SDIM + kvbase + krB)) * EDIM + h * DHDIM + kcB;
    const int vrA = sA >> 2, vcA = ((sA & 3) ^ ((vrA >> 1) & 3)) * 8;
    const int vrB = sB >> 2, vcB = ((sB & 3) ^ ((vrB >> 1) & 3)) * 8;
    const u16* vgA = Vtb + ((size_t)bh * DHDIM + vrA) * SDIM + kvbase + vcA;
    const u16* vgB = Vtb + ((size_t)bh * DHDIM + vrB) * SDIM + kvbase + vcB;
    u16* ksA = Ks + sA * 8; u16* ksB = Ks + sB * 8;
    u16* vsA = Vs + sA * 8; u16* vsB = Vs + sB * 8;

    f32x4 acc0[8], acc1[8];
#pragma unroll
    for (int d = 0; d < 8; ++d) {
        acc0[d] = (f32x4){0.f, 0.f, 0.f, 0.f};
        acc1[d] = (f32x4){0.f, 0.f, 0.f, 0.f};
    }
    f32x4 accl0 = (f32x4){0.f, 0.f, 0.f, 0.f};
    f32x4 accl1 = (f32x4){0.f, 0.f, 0.f, 0.f};

    const f32x4 z4 = (f32x4){0.f, 0.f, 0.f, 0.f};
    bf16x8 ones;
#pragma unroll
    for (int j = 0; j < 8; ++j) ones[j] = (short)0x3F80;   // bf16 1.0

    const int lx = ln & 7;
    const int vsw = (quad ^ ((ln >> 1) & 3)) * 8;

    for (int it = 0; it < 16; ++it) {
        __syncthreads();
        gload16(ksA, kgA); gload16(ksB, kgB);
        gload16(vsA, vgA); gload16(vsB, vgB);
        kgA += 32 * EDIM; kgB += 32 * EDIM; vgA += 32; vgB += 32;
        __syncthreads();

        bf16x8 kf[2][2][2];
#pragma unroll
        for (int nt = 0; nt < 2; ++nt) {
            const int rb = (nt * 16 + ln) * 16;
#pragma unroll
            for (int br = 0; br < 2; ++br)
#pragma unroll
                for (int kb = 0; kb < 2; ++kb) {
                    int kc = br * 8 + kb * 4 + quad;
                    kf[nt][br][kb] = *(const bf16x8*)&Ks[(rb + (kc ^ lx)) * 8];
                }
        }

        f32x4 s00 = __builtin_amdgcn_mfma_f32_16x16x32_bf16(aq[0][0], kf[0][0][0], z4, 0, 0, 0);
        s00 = __builtin_amdgcn_mfma_f32_16x16x32_bf16(aq[0][1], kf[0][0][1], s00, 0, 0, 0);
        f32x4 s01 = __builtin_amdgcn_mfma_f32_16x16x32_bf16(aq[0][0], kf[1][0][0], z4, 0, 0, 0);
        s01 = __builtin_amdgcn_mfma_f32_16x16x32_bf16(aq[0][1], kf[1][0][1], s01, 0, 0, 0);
        f32x4 s10 = __builtin_amdgcn_mfma_f32_16x16x32_bf16(aq[1][0], kf[0][1][0], z4, 0, 0, 0);
        s10 = __builtin_amdgcn_mfma_f32_16x16x32_bf16(aq[1][1], kf[0][1][1], s10, 0, 0, 0);
        f32x4 s11 = __builtin_amdgcn_mfma_f32_16x16x32_bf16(aq[1][0], kf[1][1][0], z4, 0, 0, 0);
        s11 = __builtin_amdgcn_mfma_f32_16x16x32_bf16(aq[1][1], kf[1][1][1], s11, 0, 0, 0);

        // ---- exp (Q pre-scaled) + wave-private P store ----
#pragma unroll
        for (int r = 0; r < 4; ++r) {
            Ps[wv][0][quad * 4 + r][ln]      = exp2f(s00[r]);
            Ps[wv][0][quad * 4 + r][16 + ln] = exp2f(s01[r]);
            Ps[wv][1][quad * 4 + r][ln]      = exp2f(s10[r]);
            Ps[wv][1][quad * 4 + r][16 + ln] = exp2f(s11[r]);
        }

        // ---- read P as A-fragment; truncate-pack bf16 via v_perm ----
        bf16x8 ap0, ap1;
        {
            union { bf16x8 v; unsigned int u[4]; } pk0, pk1;
            const float* pr0 = &Ps[wv][0][ln][quad * 8];
            f32x4 lo = *(const f32x4*)pr0;
            f32x4 hi = *(const f32x4*)(pr0 + 4);
            pk0.u[0] = __builtin_amdgcn_perm(__float_as_uint(lo[1]), __float_as_uint(lo[0]), 0x07060302u);
            pk0.u[1] = __builtin_amdgcn_perm(__float_as_uint(lo[3]), __float_as_uint(lo[2]), 0x07060302u);
            pk0.u[2] = __builtin_amdgcn_perm(__float_as_uint(hi[1]), __float_as_uint(hi[0]), 0x07060302u);
            pk0.u[3] = __builtin_amdgcn_perm(__float_as_uint(hi[3]), __float_as_uint(hi[2]), 0x07060302u);
            const float* pr1 = &Ps[wv][1][ln][quad * 8];
            f32x4 lo1 = *(const f32x4*)pr1;
            f32x4 hi1 = *(const f32x4*)(pr1 + 4);
            pk1.u[0] = __builtin_amdgcn_perm(__float_as_uint(lo1[1]), __float_as_uint(lo1[0]), 0x07060302u);
            pk1.u[1] = __builtin_amdgcn_perm(__float_as_uint(lo1[3]), __float_as_uint(lo1[2]), 0x07060302u);
            pk1.u[2] = __builtin_amdgcn_perm(__float_as_uint(hi1[1]), __float_as_uint(hi1[0]), 0x07060302u);
            pk1.u[3] = __builtin_amdgcn_perm(__float_as_uint(hi1[3]), __float_as_uint(hi1[2]), 0x07060302u);
            ap0 = pk0.v; ap1 = pk1.v;
        }

        // ---- l partial via ones-MFMA ----
        accl0 = __builtin_amdgcn_mfma_f32_16x16x32_bf16(ap0, ones, accl0, 0, 0, 0);
        accl1 = __builtin_amdgcn_mfma_f32_16x16x32_bf16(ap1, ones, accl1, 0, 0, 0);

        // ---- V B-fragments + PV ----
#pragma unroll
        for (int dt = 0; dt < 8; ++dt) {
            bf16x8 bvf = *(const bf16x8*)&Vs[(dt * 16 + ln) * 32 + vsw];
            acc0[dt] = __builtin_amdgcn_mfma_f32_16x16x32_bf16(ap0, bvf, acc0[dt], 0, 0, 0);
            acc1[dt] = __builtin_amdgcn_mfma_f32_16x16x32_bf16(ap1, bvf, acc1[dt], 0, 0, 0);
        }
    }

    // ---- atomic accumulation of partials (accl rows match epilogue rows) ----
#pragma unroll
    for (int r = 0; r < 4; ++r) {
        size_t row = (size_t)(b * SDIM + q0 + quad * 4 + r);
        float* o0 = Oacc + ((row * 8 + h) * 2 + 0) * 128 + ln;
        float* o1 = Oacc + ((row * 8 + h) * 2 + 1) * 128 + ln;
#pragma unroll
        for (int dt = 0; dt < 8; ++dt) {
            atomicAdd(o0 + dt * 16, acc0[dt][r]);
            atomicAdd(o1 + dt * 16, acc1[dt][r]);
        }
    }
    if (ln == 0) {
        float* l0 = Lacc + (size_t)((b * 8 + h) * 2 + 0) * SDIM + q0 + quad * 4;
        float* l1 = Lacc + (size_t)((b * 8 + h) * 2 + 1) * SDIM + q0 + quad * 4;
#pragma unroll
        for (int r = 0; r < 4; ++r) {
            atomicAdd(l0 + r, accl0[r]);
            atomicAdd(l1 + r, accl1[r]);
        }
    }
}

// ------------------------------------------------------------------
// combine branches + RMSNorm -> bf16 normed. Grid 4096 rows x 256 thr.
// ------------------------------------------------------------------
__global__ __launch_bounds__(256) void rms_combine(
    const float* __restrict__ Oacc, const float* __restrict__ Lacc,
    const float* __restrict__ nw, u16* __restrict__ Nb,
    const float* __restrict__ dwp)
{
    const int row = blockIdx.x;
    const int tid = threadIdx.x;
    const int h = tid >> 5, dh0 = (tid & 31) * 4;
    const int b = row >> 11, q = row & 2047;

    size_t ob = ((size_t)row * 8 + h) * 2 * 128;
    f32x4 a0 = *(const f32x4*)&Oacc[ob + dh0];
    f32x4 a1 = *(const f32x4*)&Oacc[ob + 128 + dh0];
    float l0 = Lacc[(size_t)((b * 8 + h) * 2 + 0) * SDIM + q];
    float l1 = Lacc[(size_t)((b * 8 + h) * 2 + 1) * SDIM + q];
    const float dw = dwp[0];
    float inv0 = 1.0f / l0;
    float inv1 = dw / l1;
    float o[4];
#pragma unroll
    for (int k = 0; k < 4; ++k) o[k] = a0[k] * inv0 - a1[k] * inv1;

    float ss = o[0] * o[0] + o[1] * o[1] + o[2] * o[2] + o[3] * o[3];
    ss += __shfl_xor(ss, 1,  64);
    ss += __shfl_xor(ss, 2,  64);
    ss += __shfl_xor(ss, 4,  64);
    ss += __shfl_xor(ss, 8,  64);
    ss += __shfl_xor(ss, 16, 64);
    ss += __shfl_xor(ss, 32, 64);
    __shared__ float red[4];
    if ((tid & 63) == 0) red[tid >> 6] = ss;
    __syncthreads();
    float tot = red[0] + red[1] + red[2] + red[3];
    float rms = rsqrtf(tot * (1.0f / 1024.0f) + 1.1920929e-07f);

    float4 w = *(const float4*)&nw[tid * 4];
    u16x4 pk;
    pk[0] = bf16rne(o[0] * rms * w.x);
    pk[1] = bf16rne(o[1] * rms * w.y);
    pk[2] = bf16rne(o[2] * rms * w.z);
    pk[3] = bf16rne(o[3] * rms * w.w);
    *(u16x4*)&Nb[(size_t)row * EDIM + tid * 4] = pk;
}

// ------------------------------------------------------------------
extern "C" void kernel_launch(void* const* d_in, const int* in_sizes, int n_in,
                              void* d_out, int out_size, void* d_ws, size_t ws_size,
                              hipStream_t stream)
{
    const float* x   = (const float*)d_in[0];
    const float* Wq  = (const float*)d_in[1];
    const float* Wk  = (const float*)d_in[2];
    const float* Wv  = (const float*)d_in[3];
    const float* nw  = (const float*)d_in[4];
    const float* Wo  = (const float*)d_in[5];
    const float* bo  = (const float*)d_in[6];
    const float* dwp = (const float*)d_in[7];
    float* out = (float*)d_out;

    float* Oacc = (float*)d_ws;                          // 32 MB
    u16*  xb   = (u16*)d_ws;                             // overlays Oacc head
    u16*  wob  = (u16*)((char*)d_ws + 33554432);         // 2 MB
    u16*  wqb  = wob + 1048576;
    u16*  wkb  = wqb + 1048576;
    u16*  wvb  = wkb + 1048576;
    float* Lacc = (float*)wqb;                           // overlays wqb (dead)
    u16*  Qb   = wvb + 1048576;                          // 8 MB
    u16*  Kb   = Qb + 4194304;
    u16*  Vtb  = Kb + 4194304;
    u16*  Nb   = Qb;                                     // overlays Qb (dead)

    cast_bf16<<<4096, 256, 0, stream>>>(x, Wq, Wk, Wv, Wo,
                                        xb, wqb, wkb, wvb, wob);
    gemm_qkv<<<dim3(GN / 128, GM / 128, 3), 256, 0, stream>>>(
        xb, wqb, wkb, wvb, Qb, Kb, Vtb);
    zero_ws<<<8256, 256, 0, stream>>>(Oacc, Lacc);
    attn_mfma<<<dim3(SDIM / 64, 2 * HDIM, 4), 256, 0, stream>>>(
        Qb, Kb, Vtb, Oacc, Lacc);
    rms_combine<<<4096, 256, 0, stream>>>(Oacc, Lacc, nw, Nb, dwp);
    gemm_out<<<dim3(GN / 128, GM / 128, 1), 256, 0, stream>>>(
        Nb, wob, out, bo, dwp);
}

// Round 6
// 308.246 us; speedup vs baseline: 1.1597x; 1.1597x over previous
//
#include <hip/hip_runtime.h>
#include <hip/hip_bf16.h>
#include <math.h>

// MultiHeadDiffAttention, MI355X. Round 6: R5 VALU trims + kv-split
// reverted to x2 (atomic epilogue amortized over 32 iters) + 4 blocks/CU
// (grid 1024 fully co-resident: LDS 34.8KB, VGPR<=64, bounds(256,4)).
// B=2 S=2048 E=1024 H=8 DH=128 F=64.
// ws layout (64 MB):
//   [Oacc 32MB f32 (xb bf16 overlays head, dead before zero_ws)]
//   [wob 2MB][wqb 2MB <- Lacc overlays after gemm_qkv][wkb 2][wvb 2]
//   [Qb 8MB <- Nb overlays after attn][Kb 8MB][Vtb 8MB]

#define SDIM 2048
#define EDIM 1024
#define HDIM 8
#define DHDIM 128

typedef unsigned short u16;
typedef __attribute__((ext_vector_type(8))) short bf16x8;
typedef __attribute__((ext_vector_type(4))) u16 u16x4;
typedef __attribute__((ext_vector_type(8))) u16 u16x8;
typedef __attribute__((ext_vector_type(4))) float f32x4;

__device__ __forceinline__ u16 bf16rne(float f) {
    unsigned int u = __float_as_uint(f);
    u += 0x7fff + ((u >> 16) & 1);
    return (u16)(u >> 16);
}

__device__ __forceinline__ void gload16(void* lds, const void* g) {
    __builtin_amdgcn_global_load_lds(
        (const __attribute__((address_space(1))) unsigned int*)g,
        (__attribute__((address_space(3))) unsigned int*)lds, 16, 0, 0);
}

constexpr int GM = 4096, GN = 1024, GK = 1024;

// ------------------------------------------------------------------
// cast fp32 -> bf16: x (4M) + Wq/Wk/Wv/Wo (1M each).
// ------------------------------------------------------------------
__global__ __launch_bounds__(256) void cast_bf16(
    const float* __restrict__ x,  const float* __restrict__ wq,
    const float* __restrict__ wk, const float* __restrict__ wv,
    const float* __restrict__ wo,
    u16* __restrict__ xb,  u16* __restrict__ wqb, u16* __restrict__ wkb,
    u16* __restrict__ wvb, u16* __restrict__ wob)
{
    int bid = blockIdx.x;
    const float* src; u16* dst; int lb;
    if (bid < 2048)      { src = x;  dst = xb;  lb = bid; }
    else if (bid < 2560) { src = wq; dst = wqb; lb = bid - 2048; }
    else if (bid < 3072) { src = wk; dst = wkb; lb = bid - 2560; }
    else if (bid < 3584) { src = wv; dst = wvb; lb = bid - 3072; }
    else                 { src = wo; dst = wob; lb = bid - 3584; }
    size_t i = ((size_t)lb * 256 + threadIdx.x) * 8;
    float4 a = *(const float4*)&src[i];
    float4 b = *(const float4*)&src[i + 4];
    u16x8 o;
    o[0] = bf16rne(a.x); o[1] = bf16rne(a.y); o[2] = bf16rne(a.z); o[3] = bf16rne(a.w);
    o[4] = bf16rne(b.x); o[5] = bf16rne(b.y); o[6] = bf16rne(b.z); o[7] = bf16rne(b.w);
    *(u16x8*)&dst[i] = o;
}

// ------------------------------------------------------------------
// zero Oacc (8.39M f32) + Lacc (64K f32)
// ------------------------------------------------------------------
__global__ __launch_bounds__(256) void zero_ws(
    float* __restrict__ Oacc, float* __restrict__ Lacc)
{
    int bid = blockIdx.x;
    const f32x4 z = (f32x4){0.f, 0.f, 0.f, 0.f};
    if (bid < 8192) {
        *(f32x4*)&Oacc[((size_t)bid * 256 + threadIdx.x) * 4] = z;
    } else {
        *(f32x4*)&Lacc[((size_t)(bid - 8192) * 256 + threadIdx.x) * 4] = z;
    }
}

// ------------------------------------------------------------------
// bf16 MFMA GEMM core: C = A @ W^T, 128x128, BK=32. (unchanged)
// ------------------------------------------------------------------
struct GemmCore {
    f32x4 acc[4][4];
    int m0, n0, wm, wn, ln, quad;
};

__device__ __forceinline__ void gemm_core(
    GemmCore& g, const u16* __restrict__ A, const u16* __restrict__ W,
    u16* AsBase, u16* BsBase)
{
    const int tid = threadIdx.x;
    const int lane = tid & 63;
    const int wv = tid >> 6;
    g.ln = lane & 15; g.quad = lane >> 4;
    g.wm = (wv >> 1) * 64; g.wn = (wv & 1) * 64;
    g.m0 = blockIdx.y * 128; g.n0 = blockIdx.x * 128;

#pragma unroll
    for (int i = 0; i < 4; ++i)
#pragma unroll
        for (int j = 0; j < 4; ++j)
            g.acc[i][j] = (f32x4){0.f, 0.f, 0.f, 0.f};

    const int s0 = tid, s1 = tid + 256;
    const int ar0 = s0 >> 2, ac0 = (((s0 & 3) ^ ((ar0 >> 1) & 3)) * 8);
    const int ar1 = s1 >> 2, ac1 = (((s1 & 3) ^ ((ar1 >> 1) & 3)) * 8);
    const u16* pa0 = A + (size_t)(g.m0 + ar0) * GK + ac0;
    const u16* pa1 = A + (size_t)(g.m0 + ar1) * GK + ac1;
    const u16* pb0 = W + (size_t)(g.n0 + ar0) * GK + ac0;
    const u16* pb1 = W + (size_t)(g.n0 + ar1) * GK + ac1;
    u16* la0 = AsBase + s0 * 8; u16* la1 = AsBase + s1 * 8;
    u16* lb0 = BsBase + s0 * 8; u16* lb1 = BsBase + s1 * 8;

    const int roff = ((g.quad ^ ((g.ln >> 1) & 3)) * 8);

    for (int k0 = 0; k0 < GK; k0 += 32) {
        gload16(la0, pa0 + k0);
        gload16(la1, pa1 + k0);
        gload16(lb0, pb0 + k0);
        gload16(lb1, pb1 + k0);
        __syncthreads();

        bf16x8 af[4], bfr[4];
#pragma unroll
        for (int t = 0; t < 4; ++t) {
            af[t]  = *(const bf16x8*)&AsBase[(g.wm + t * 16 + g.ln) * 32 + roff];
            bfr[t] = *(const bf16x8*)&BsBase[(g.wn + t * 16 + g.ln) * 32 + roff];
        }
#pragma unroll
        for (int i = 0; i < 4; ++i)
#pragma unroll
            for (int j = 0; j < 4; ++j)
                g.acc[i][j] = __builtin_amdgcn_mfma_f32_16x16x32_bf16(
                    af[i], bfr[j], g.acc[i][j], 0, 0, 0);
        __syncthreads();
    }
}

// z=0 -> Qb (bf16, PRE-SCALED by 0.125*log2e), z=1 -> Kb, z=2 -> Vt
__global__ __launch_bounds__(256) void gemm_qkv(
    const u16* __restrict__ A,
    const u16* __restrict__ W0, const u16* __restrict__ W1, const u16* __restrict__ W2,
    u16* __restrict__ Qb, u16* __restrict__ Kb, u16* __restrict__ Vtb)
{
    __shared__ u16 As[128 * 32];
    __shared__ u16 Bs[128 * 32];
    const int z = blockIdx.z;
    const u16* W = (z == 0) ? W0 : ((z == 1) ? W1 : W2);
    GemmCore g;
    gemm_core(g, A, W, As, Bs);

    if (z < 2) {
        const float scl = (z == 0) ? 0.125f * 1.44269504f : 1.0f;
        u16* C = (z == 0) ? Qb : Kb;
#pragma unroll
        for (int i = 0; i < 4; ++i) {
            int rb = g.m0 + g.wm + i * 16 + g.quad * 4;
#pragma unroll
            for (int r = 0; r < 4; ++r) {
                u16* crow = C + (size_t)(rb + r) * GN + g.n0 + g.wn + g.ln;
#pragma unroll
                for (int j = 0; j < 4; ++j)
                    crow[j * 16] = bf16rne(g.acc[i][j][r] * scl);
            }
        }
    } else {
        const int bb = g.m0 >> 11;
        const int sb = (g.m0 & 2047) + g.wm + g.quad * 4;
#pragma unroll
        for (int j = 0; j < 4; ++j) {
            int dhg = g.n0 + g.wn + j * 16 + g.ln;
            int hh = dhg >> 7, dh = dhg & 127;
            u16* vrow = Vtb + ((size_t)(bb * 8 + hh) * DHDIM + dh) * SDIM + sb;
#pragma unroll
            for (int i = 0; i < 4; ++i) {
                u16x4 pk;
#pragma unroll
                for (int r = 0; r < 4; ++r) pk[r] = bf16rne(g.acc[i][j][r]);
                *(u16x4*)&vrow[i * 16] = pk;
            }
        }
    }
}

// out = (A @ W.T + bias) * (1-dw), fp32 output
__global__ __launch_bounds__(256) void gemm_out(
    const u16* __restrict__ A, const u16* __restrict__ W,
    float* __restrict__ C, const float* __restrict__ bias,
    const float* __restrict__ dwp)
{
    __shared__ u16 As[128 * 32];
    __shared__ u16 Bs[128 * 32];
    GemmCore g;
    gemm_core(g, A, W, As, Bs);

    const float scale = 1.0f - dwp[0];
    float bv[4];
#pragma unroll
    for (int j = 0; j < 4; ++j) bv[j] = bias[g.n0 + g.wn + j * 16 + g.ln];
#pragma unroll
    for (int i = 0; i < 4; ++i) {
        int rb = g.m0 + g.wm + i * 16 + g.quad * 4;
#pragma unroll
        for (int r = 0; r < 4; ++r) {
            float* crow = C + (size_t)(rb + r) * GN + g.n0 + g.wn + g.ln;
#pragma unroll
            for (int j = 0; j < 4; ++j)
                crow[j * 16] = (g.acc[i][j][r] + bv[j]) * scale;
        }
    }
}

// ------------------------------------------------------------------
// MFMA diff attention v4. Block = 4 waves, 64 q rows.
// Grid (32 qtiles, 16 bh, 2 kv-parts) = 1024 blocks, ALL co-resident
// at 4 blocks/CU (LDS 34.8KB, VGPR<=64). 32 iters of BKV=32.
// Q pre-scaled -> p = exp2f(s). P pack via v_perm truncation.
// l via ones-MFMA. Partials additive -> fp32 atomicAdd.
// ------------------------------------------------------------------
__global__ __launch_bounds__(256, 4) void attn_mfma(
    const u16* __restrict__ Qb, const u16* __restrict__ Kb,
    const u16* __restrict__ Vtb,
    float* __restrict__ Oacc, float* __restrict__ Lacc)
{
    __shared__ u16 Ks[512 * 8];
    __shared__ u16 Vs[512 * 8];
    __shared__ float Ps[4][2][16][36];

    const int tid = threadIdx.x;
    const int wv   = tid >> 6;
    const int lane = tid & 63;
    const int ln = lane & 15, quad = lane >> 4;
    const int bh = blockIdx.y, b = bh >> 3, h = bh & 7;
    const int q0 = blockIdx.x * 64 + wv * 16;
    const int kvbase = blockIdx.z * 1024;

    const size_t qoff = (size_t)b * SDIM * EDIM + h * DHDIM;
    const u16* qp = Qb + qoff + (size_t)(q0 + ln) * EDIM + quad * 8;
    bf16x8 aq[2][2];
    aq[0][0] = *(const bf16x8*)(qp);
    aq[0][1] = *(const bf16x8*)(qp + 32);
    aq[1][0] = *(const bf16x8*)(qp + 64);
    aq[1][1] = *(const bf16x8*)(qp + 96);

    const int sA = tid, sB = tid + 256;
    const int krA = sA >> 4, kcA = ((sA & 15) ^ (krA & 7)) * 8;
    const int krB = sB >> 4, kcB = ((sB & 15) ^ (krB & 7)) * 8;
    const u16* kgA = Kb + ((size_t)(b * SDIM + kvbase + krA)) * EDIM + h * DHDIM + kcA;
    const u16* kgB = Kb + ((size_t)(b * SDIM + kvbase + krB)) * EDIM + h * DHDIM + kcB;
    const int vrA = sA >> 2, vcA = ((sA & 3) ^ ((vrA >> 1) & 3)) * 8;
    const int vrB = sB >> 2, vcB = ((sB & 3) ^ ((vrB >> 1) & 3)) * 8;
    const u16* vgA = Vtb + ((size_t)bh * DHDIM + vrA) * SDIM + kvbase + vcA;
    const u16* vgB = Vtb + ((size_t)bh * DHDIM + vrB) * SDIM + kvbase + vcB;
    u16* ksA = Ks + sA * 8; u16* ksB = Ks + sB * 8;
    u16* vsA = Vs + sA * 8; u16* vsB = Vs + sB * 8;

    f32x4 acc0[8], acc1[8];
#pragma unroll
    for (int d = 0; d < 8; ++d) {
        acc0[d] = (f32x4){0.f, 0.f, 0.f, 0.f};
        acc1[d] = (f32x4){0.f, 0.f, 0.f, 0.f};
    }
    f32x4 accl0 = (f32x4){0.f, 0.f, 0.f, 0.f};
    f32x4 accl1 = (f32x4){0.f, 0.f, 0.f, 0.f};

    const f32x4 z4 = (f32x4){0.f, 0.f, 0.f, 0.f};
    bf16x8 ones;
#pragma unroll
    for (int j = 0; j < 8; ++j) ones[j] = (short)0x3F80;   // bf16 1.0

    const int lx = ln & 7;
    const int vsw = (quad ^ ((ln >> 1) & 3)) * 8;

    for (int it = 0; it < 32; ++it) {
        __syncthreads();
        gload16(ksA, kgA); gload16(ksB, kgB);
        gload16(vsA, vgA); gload16(vsB, vgB);
        kgA += 32 * EDIM; kgB += 32 * EDIM; vgA += 32; vgB += 32;
        __syncthreads();

        bf16x8 kf[2][2][2];
#pragma unroll
        for (int nt = 0; nt < 2; ++nt) {
            const int rb = (nt * 16 + ln) * 16;
#pragma unroll
            for (int br = 0; br < 2; ++br)
#pragma unroll
                for (int kb = 0; kb < 2; ++kb) {
                    int kc = br * 8 + kb * 4 + quad;
                    kf[nt][br][kb] = *(const bf16x8*)&Ks[(rb + (kc ^ lx)) * 8];
                }
        }

        f32x4 s00 = __builtin_amdgcn_mfma_f32_16x16x32_bf16(aq[0][0], kf[0][0][0], z4, 0, 0, 0);
        s00 = __builtin_amdgcn_mfma_f32_16x16x32_bf16(aq[0][1], kf[0][0][1], s00, 0, 0, 0);
        f32x4 s01 = __builtin_amdgcn_mfma_f32_16x16x32_bf16(aq[0][0], kf[1][0][0], z4, 0, 0, 0);
        s01 = __builtin_amdgcn_mfma_f32_16x16x32_bf16(aq[0][1], kf[1][0][1], s01, 0, 0, 0);
        f32x4 s10 = __builtin_amdgcn_mfma_f32_16x16x32_bf16(aq[1][0], kf[0][1][0], z4, 0, 0, 0);
        s10 = __builtin_amdgcn_mfma_f32_16x16x32_bf16(aq[1][1], kf[0][1][1], s10, 0, 0, 0);
        f32x4 s11 = __builtin_amdgcn_mfma_f32_16x16x32_bf16(aq[1][0], kf[1][1][0], z4, 0, 0, 0);
        s11 = __builtin_amdgcn_mfma_f32_16x16x32_bf16(aq[1][1], kf[1][1][1], s11, 0, 0, 0);

        // ---- exp (Q pre-scaled) + wave-private P store ----
#pragma unroll
        for (int r = 0; r < 4; ++r) {
            Ps[wv][0][quad * 4 + r][ln]      = exp2f(s00[r]);
            Ps[wv][0][quad * 4 + r][16 + ln] = exp2f(s01[r]);
            Ps[wv][1][quad * 4 + r][ln]      = exp2f(s10[r]);
            Ps[wv][1][quad * 4 + r][16 + ln] = exp2f(s11[r]);
        }

        // ---- read P as A-fragment; truncate-pack bf16 via v_perm ----
        bf16x8 ap0, ap1;
        {
            union { bf16x8 v; unsigned int u[4]; } pk0, pk1;
            const float* pr0 = &Ps[wv][0][ln][quad * 8];
            f32x4 lo = *(const f32x4*)pr0;
            f32x4 hi = *(const f32x4*)(pr0 + 4);
            pk0.u[0] = __builtin_amdgcn_perm(__float_as_uint(lo[1]), __float_as_uint(lo[0]), 0x07060302u);
            pk0.u[1] = __builtin_amdgcn_perm(__float_as_uint(lo[3]), __float_as_uint(lo[2]), 0x07060302u);
            pk0.u[2] = __builtin_amdgcn_perm(__float_as_uint(hi[1]), __float_as_uint(hi[0]), 0x07060302u);
            pk0.u[3] = __builtin_amdgcn_perm(__float_as_uint(hi[3]), __float_as_uint(hi[2]), 0x07060302u);
            const float* pr1 = &Ps[wv][1][ln][quad * 8];
            f32x4 lo1 = *(const f32x4*)pr1;
            f32x4 hi1 = *(const f32x4*)(pr1 + 4);
            pk1.u[0] = __builtin_amdgcn_perm(__float_as_uint(lo1[1]), __float_as_uint(lo1[0]), 0x07060302u);
            pk1.u[1] = __builtin_amdgcn_perm(__float_as_uint(lo1[3]), __float_as_uint(lo1[2]), 0x07060302u);
            pk1.u[2] = __builtin_amdgcn_perm(__float_as_uint(hi1[1]), __float_as_uint(hi1[0]), 0x07060302u);
            pk1.u[3] = __builtin_amdgcn_perm(__float_as_uint(hi1[3]), __float_as_uint(hi1[2]), 0x07060302u);
            ap0 = pk0.v; ap1 = pk1.v;
        }

        // ---- l partial via ones-MFMA ----
        accl0 = __builtin_amdgcn_mfma_f32_16x16x32_bf16(ap0, ones, accl0, 0, 0, 0);
        accl1 = __builtin_amdgcn_mfma_f32_16x16x32_bf16(ap1, ones, accl1, 0, 0, 0);

        // ---- V B-fragments + PV ----
#pragma unroll
        for (int dt = 0; dt < 8; ++dt) {
            bf16x8 bvf = *(const bf16x8*)&Vs[(dt * 16 + ln) * 32 + vsw];
            acc0[dt] = __builtin_amdgcn_mfma_f32_16x16x32_bf16(ap0, bvf, acc0[dt], 0, 0, 0);
            acc1[dt] = __builtin_amdgcn_mfma_f32_16x16x32_bf16(ap1, bvf, acc1[dt], 0, 0, 0);
        }
    }

    // ---- atomic accumulation of partials ----
#pragma unroll
    for (int r = 0; r < 4; ++r) {
        size_t row = (size_t)(b * SDIM + q0 + quad * 4 + r);
        float* o0 = Oacc + ((row * 8 + h) * 2 + 0) * 128 + ln;
        float* o1 = Oacc + ((row * 8 + h) * 2 + 1) * 128 + ln;
#pragma unroll
        for (int dt = 0; dt < 8; ++dt) {
            atomicAdd(o0 + dt * 16, acc0[dt][r]);
            atomicAdd(o1 + dt * 16, acc1[dt][r]);
        }
    }
    if (ln == 0) {
        float* l0 = Lacc + (size_t)((b * 8 + h) * 2 + 0) * SDIM + q0 + quad * 4;
        float* l1 = Lacc + (size_t)((b * 8 + h) * 2 + 1) * SDIM + q0 + quad * 4;
#pragma unroll
        for (int r = 0; r < 4; ++r) {
            atomicAdd(l0 + r, accl0[r]);
            atomicAdd(l1 + r, accl1[r]);
        }
    }
}

// ------------------------------------------------------------------
// combine branches + RMSNorm -> bf16 normed. Grid 4096 rows x 256 thr.
// ------------------------------------------------------------------
__global__ __launch_bounds__(256) void rms_combine(
    const float* __restrict__ Oacc, const float* __restrict__ Lacc,
    const float* __restrict__ nw, u16* __restrict__ Nb,
    const float* __restrict__ dwp)
{
    const int row = blockIdx.x;
    const int tid = threadIdx.x;
    const int h = tid >> 5, dh0 = (tid & 31) * 4;
    const int b = row >> 11, q = row & 2047;

    size_t ob = ((size_t)row * 8 + h) * 2 * 128;
    f32x4 a0 = *(const f32x4*)&Oacc[ob + dh0];
    f32x4 a1 = *(const f32x4*)&Oacc[ob + 128 + dh0];
    float l0 = Lacc[(size_t)((b * 8 + h) * 2 + 0) * SDIM + q];
    float l1 = Lacc[(size_t)((b * 8 + h) * 2 + 1) * SDIM + q];
    const float dw = dwp[0];
    float inv0 = 1.0f / l0;
    float inv1 = dw / l1;
    float o[4];
#pragma unroll
    for (int k = 0; k < 4; ++k) o[k] = a0[k] * inv0 - a1[k] * inv1;

    float ss = o[0] * o[0] + o[1] * o[1] + o[2] * o[2] + o[3] * o[3];
    ss += __shfl_xor(ss, 1,  64);
    ss += __shfl_xor(ss, 2,  64);
    ss += __shfl_xor(ss, 4,  64);
    ss += __shfl_xor(ss, 8,  64);
    ss += __shfl_xor(ss, 16, 64);
    ss += __shfl_xor(ss, 32, 64);
    __shared__ float red[4];
    if ((tid & 63) == 0) red[tid >> 6] = ss;
    __syncthreads();
    float tot = red[0] + red[1] + red[2] + red[3];
    float rms = rsqrtf(tot * (1.0f / 1024.0f) + 1.1920929e-07f);

    float4 w = *(const float4*)&nw[tid * 4];
    u16x4 pk;
    pk[0] = bf16rne(o[0] * rms * w.x);
    pk[1] = bf16rne(o[1] * rms * w.y);
    pk[2] = bf16rne(o[2] * rms * w.z);
    pk[3] = bf16rne(o[3] * rms * w.w);
    *(u16x4*)&Nb[(size_t)row * EDIM + tid * 4] = pk;
}

// ------------------------------------------------------------------
extern "C" void kernel_launch(void* const* d_in, const int* in_sizes, int n_in,
                              void* d_out, int out_size, void* d_ws, size_t ws_size,
                              hipStream_t stream)
{
    const float* x   = (const float*)d_in[0];
    const float* Wq  = (const float*)d_in[1];
    const float* Wk  = (const float*)d_in[2];
    const float* Wv  = (const float*)d_in[3];
    const float* nw  = (const float*)d_in[4];
    const float* Wo  = (const float*)d_in[5];
    const float* bo  = (const float*)d_in[6];
    const float* dwp = (const float*)d_in[7];
    float* out = (float*)d_out;

    float* Oacc = (float*)d_ws;                          // 32 MB
    u16*  xb   = (u16*)d_ws;                             // overlays Oacc head
    u16*  wob  = (u16*)((char*)d_ws + 33554432);         // 2 MB
    u16*  wqb  = wob + 1048576;
    u16*  wkb  = wqb + 1048576;
    u16*  wvb  = wkb + 1048576;
    float* Lacc = (float*)wqb;                           // overlays wqb (dead)
    u16*  Qb   = wvb + 1048576;                          // 8 MB
    u16*  Kb   = Qb + 4194304;
    u16*  Vtb  = Kb + 4194304;
    u16*  Nb   = Qb;                                     // overlays Qb (dead)

    cast_bf16<<<4096, 256, 0, stream>>>(x, Wq, Wk, Wv, Wo,
                                        xb, wqb, wkb, wvb, wob);
    gemm_qkv<<<dim3(GN / 128, GM / 128, 3), 256, 0, stream>>>(
        xb, wqb, wkb, wvb, Qb, Kb, Vtb);
    zero_ws<<<8256, 256, 0, stream>>>(Oacc, Lacc);
    attn_mfma<<<dim3(SDIM / 64, 2 * HDIM, 2), 256, 0, stream>>>(
        Qb, Kb, Vtb, Oacc, Lacc);
    rms_combine<<<4096, 256, 0, stream>>>(Oacc, Lacc, nw, Nb, dwp);
    gemm_out<<<dim3(GN / 128, GM / 128, 1), 256, 0, stream>>>(
        Nb, wob, out, bo, dwp);
}